// Round 3
// baseline (533.622 us; speedup 1.0000x reference)
//
#include <hip/hip_runtime.h>
#include <stdint.h>

#define DEVI __device__ __forceinline__

typedef __bf16 bf16x8 __attribute__((ext_vector_type(8)));
typedef float  floatx16 __attribute__((ext_vector_type(16)));

// B=8, S=2048, H=1024. M = B*S = 16384.
// ws: Q @0 (32MiB, pre-scaled 1/32) | K @+32M | Vt @+64M ([8][1024 d][2048 k])
//     lvec @+96M (f32[16384]) | P @+96M+64K (bf16 [8][2048][2048]);
//     P region overlays Xb (32MiB) + Wt (6MiB), dead before P written.

DEVI unsigned short f2bf(float f) {
  union { float f; uint32_t u; } x; x.f = f;
  return (unsigned short)((x.u + 0x7fffu + ((x.u >> 16) & 1u)) >> 16);
}
DEVI float bf2f(unsigned short s) {
  union { uint32_t u; float f; } x; x.u = ((uint32_t)s) << 16;
  return x.f;
}

// ---------------- fused prep: X->bf16, 3x W transpose->bf16, lvec=0 ----------------
__global__ __launch_bounds__(256) void k_prep(
    const float* __restrict__ X, unsigned short* __restrict__ Xb,
    const float* __restrict__ Wq, const float* __restrict__ Wk,
    const float* __restrict__ Wv, unsigned short* __restrict__ Wt,
    float* __restrict__ lvec) {
  __shared__ float tile[64][65];
  int bx = blockIdx.x, t = threadIdx.x;
  if (bx < 16384) {                 // convert X: 4194304 float4 groups
    int i = bx * 256 + t;
    float4 v = ((const float4*)X)[i];
    ushort4 o;
    o.x = f2bf(v.x); o.y = f2bf(v.y); o.z = f2bf(v.z); o.w = f2bf(v.w);
    ((ushort4*)Xb)[i] = o;
  } else if (bx < 17152) {          // 3 x 256 transpose blocks
    int idx = bx - 16384;
    int sel = idx >> 8, b2 = idx & 255;
    const float* W = sel == 0 ? Wq : (sel == 1 ? Wk : Wv);
    unsigned short* Wo = Wt + ((size_t)sel << 20);
    int h0 = (b2 & 15) * 64, d0 = (b2 >> 4) * 64;
#pragma unroll
    for (int i = 0; i < 16; ++i) {
      int idx2 = i * 256 + t; int r = idx2 >> 6, c = idx2 & 63;
      tile[r][c] = W[(size_t)(h0 + r) * 1024 + d0 + c];
    }
    __syncthreads();
#pragma unroll
    for (int i = 0; i < 16; ++i) {
      int idx2 = i * 256 + t; int r = idx2 >> 6, c = idx2 & 63;
      Wo[(size_t)(d0 + r) * 1024 + h0 + c] = f2bf(tile[c][r]);
    }
  } else {                          // zero lvec (16384 f32)
    float4 z4 = {0.f, 0.f, 0.f, 0.f};
#pragma unroll
    for (int i = 0; i < 16; ++i) ((float4*)lvec)[i * 256 + t] = z4;
  }
}

// ---------------- async 16B global -> LDS ----------------
DEVI void gl_lds16(const unsigned short* gp, unsigned short* lp) {
  __builtin_amdgcn_global_load_lds(
      (const __attribute__((address_space(1))) void*)gp,
      (__attribute__((address_space(3))) void*)lp, 16, 0, 0);
}

// ---------------- C = A * Bt^T, 128x128 tile, BK=64, mfma_32x32x16_bf16 ----------------
// 4 waves, each a 64x64 quadrant = 2x2 of 32x32 tiles (16 regs acc each).
// LDS 16B-unit XOR swizzle c' = c ^ (row&7) for staging/frag reads.
// Epilogue goes through SMEM (unit swizzle ^ (row&15)) -> coalesced 16B stores.
// A frag: m=lane&31, k=half*8+j (half=lane>>5). B symmetric.
// C/D: col=lane&31, row=(reg&3)+8*(reg>>2)+4*half  [m74/m101]
// EPI: 4 = fused QKV (sel=blockIdx.y>>3): Q (x+b)/32, K x+b, V -> Vt[b][d][k]
//      2 = P = exp(S) masked, bf16; atomic row sums -> lsum
//      3 = O = (P*V) * 1/lvec[row], f32
template <int EPI>
__global__ __launch_bounds__(256) void k_gemm(
    const unsigned short* __restrict__ A, const unsigned short* __restrict__ Bt,
    void* __restrict__ Cv,
    const float* __restrict__ bias_q, const float* __restrict__ bias_k,
    const float* __restrict__ bias_v,
    const float* __restrict__ lvec, float* __restrict__ lsum,
    const int* __restrict__ mask,
    long aZ, long bZ, int ldA, int ldB, int kIters)
{
  __shared__ unsigned short SMEM[16384];   // 32 KiB: As | Bs, reused by epilogue
  unsigned short* As = SMEM;
  unsigned short* Bs = SMEM + 8192;
  const int t = threadIdx.x, w = t >> 6, l = t & 63;
  const int l31 = l & 31, half = l >> 5;
  const int m0 = blockIdx.x * 128;
  const int z = blockIdx.z;

  int n0, sel = 0;
  if constexpr (EPI == 4) { sel = blockIdx.y >> 3; n0 = (blockIdx.y & 7) * 128; }
  else n0 = blockIdx.y * 128;

  const unsigned short* Az = A + (size_t)z * aZ;
  const unsigned short* Bz = (EPI == 4) ? (Bt + ((size_t)sel << 20))
                                        : (Bt + (size_t)z * bZ);

  floatx16 acc[2][2];
#pragma unroll
  for (int i = 0; i < 2; ++i)
#pragma unroll
    for (int j = 0; j < 2; ++j)
#pragma unroll
      for (int r = 0; r < 16; ++r) acc[i][j][r] = 0.f;

  for (int kt = 0; kt < kIters; ++kt) {
    __syncthreads();
#pragma unroll
    for (int i = 0; i < 4; ++i) {
      int u   = (i * 4 + w) * 64 + l;   // 16B-unit index in [0,1024)
      int row = u >> 3;
      int cc  = (u & 7) ^ (row & 7);
      gl_lds16(Az + (size_t)(m0 + row) * ldA + kt * 64 + cc * 8,
               &As[(i * 4 + w) * 512]);
      gl_lds16(Bz + (size_t)(n0 + row) * ldB + kt * 64 + cc * 8,
               &Bs[(i * 4 + w) * 512]);
    }
    __syncthreads();
#pragma unroll
    for (int ks = 0; ks < 4; ++ks) {
      bf16x8 af[2], bfr[2];
#pragma unroll
      for (int ms = 0; ms < 2; ++ms) {
        int r  = (w & 1) * 64 + ms * 32 + l31;
        int cc = (ks * 2 + half) ^ (r & 7);
        af[ms] = *(const bf16x8*)&As[r * 64 + cc * 8];
      }
#pragma unroll
      for (int ns = 0; ns < 2; ++ns) {
        int r  = (w >> 1) * 64 + ns * 32 + l31;
        int cc = (ks * 2 + half) ^ (r & 7);
        bfr[ns] = *(const bf16x8*)&Bs[r * 64 + cc * 8];
      }
#pragma unroll
      for (int ms = 0; ms < 2; ++ms)
#pragma unroll
        for (int ns = 0; ns < 2; ++ns)
          acc[ms][ns] = __builtin_amdgcn_mfma_f32_32x32x16_bf16(
              af[ms], bfr[ns], acc[ms][ns], 0, 0, 0);
    }
  }

  const int wm = (w & 1) * 64, wn = (w >> 1) * 64;
  __syncthreads();  // all frag reads done before SMEM reuse

  if constexpr (EPI == 4) {
    const float* bs = sel == 0 ? bias_q : (sel == 1 ? bias_k : bias_v);
    const float sc = (sel == 0) ? 0.03125f : 1.0f;
    if (sel < 2) {
      // stage row-major bf16 [128 rows][128 cols], unit swizzle ^(row&15)
#pragma unroll
      for (int ns = 0; ns < 2; ++ns) {
        int col = wn + ns * 32 + l31;
        float bv = bs[n0 + col];
#pragma unroll
        for (int ms = 0; ms < 2; ++ms)
#pragma unroll
          for (int r = 0; r < 16; ++r) {
            int row = wm + ms * 32 + (r & 3) + ((r >> 2) << 3) + (half << 2);
            SMEM[row * 128 + (((col >> 3) ^ (row & 15)) << 3) + (col & 7)] =
                f2bf((acc[ms][ns][r] + bv) * sc);
          }
      }
      __syncthreads();
      unsigned short* C = (unsigned short*)Cv + ((size_t)sel << 24);
      int row = t >> 1, part = t & 1;
      unsigned short* gp = C + (size_t)(m0 + row) * 1024 + n0 + part * 64;
#pragma unroll
      for (int i = 0; i < 8; ++i) {
        int u = part * 8 + i;
        uint4 vv = *(const uint4*)&SMEM[row * 128 + ((u ^ (row & 15)) << 3)];
        *(uint4*)(gp + i * 8) = vv;
      }
    } else {
      // V: stage transposed [n' rows][m' cols]
#pragma unroll
      for (int ns = 0; ns < 2; ++ns) {
        int rl = wn + ns * 32 + l31;              // n' (d index)
        float bv = bs[n0 + rl];
#pragma unroll
        for (int ms = 0; ms < 2; ++ms)
#pragma unroll
          for (int r = 0; r < 16; ++r) {
            int cl = wm + ms * 32 + (r & 3) + ((r >> 2) << 3) + (half << 2); // m'
            SMEM[rl * 128 + (((cl >> 3) ^ (rl & 15)) << 3) + (cl & 7)] =
                f2bf(acc[ms][ns][r] + bv);
          }
      }
      __syncthreads();
      unsigned short* C = (unsigned short*)Cv + ((size_t)2 << 24);
      int bb = m0 >> 11, mk = m0 & 2047;
      int row = t >> 1, part = t & 1;             // row = d within tile
      unsigned short* gp = C + ((size_t)bb << 21) + ((size_t)(n0 + row) << 11)
                         + mk + part * 64;
#pragma unroll
      for (int i = 0; i < 8; ++i) {
        int u = part * 8 + i;
        uint4 vv = *(const uint4*)&SMEM[row * 128 + ((u ^ (row & 15)) << 3)];
        *(uint4*)(gp + i * 8) = vv;
      }
    }
  } else if constexpr (EPI == 2) {
    // P = exp(S) masked (max-free: |S|<=~6), stage bf16 + atomic rowsums
    const int* mz = mask + z * 2048;
    float rowsum[2][16];
#pragma unroll
    for (int ms = 0; ms < 2; ++ms)
#pragma unroll
      for (int r = 0; r < 16; ++r) rowsum[ms][r] = 0.f;
#pragma unroll
    for (int ns = 0; ns < 2; ++ns) {
      int col = wn + ns * 32 + l31;
      int mv = mz[n0 + col];
#pragma unroll
      for (int ms = 0; ms < 2; ++ms)
#pragma unroll
        for (int r = 0; r < 16; ++r) {
          int row = wm + ms * 32 + (r & 3) + ((r >> 2) << 3) + (half << 2);
          float e = mv ? __expf(acc[ms][ns][r]) : 0.f;
          unsigned short pb = f2bf(e);
          SMEM[row * 128 + (((col >> 3) ^ (row & 15)) << 3) + (col & 7)] = pb;
          rowsum[ms][r] += bf2f(pb);
        }
    }
    // reduce across the 32 col-lanes (offsets stay within each half)
#pragma unroll
    for (int ms = 0; ms < 2; ++ms)
#pragma unroll
      for (int r = 0; r < 16; ++r) {
        float s = rowsum[ms][r];
#pragma unroll
        for (int off = 1; off < 32; off <<= 1) s += __shfl_xor(s, off);
        if (l31 == 0) {
          int row = wm + ms * 32 + (r & 3) + ((r >> 2) << 3) + (half << 2);
          atomicAdd(&lsum[z * 2048 + m0 + row], s);
        }
      }
    __syncthreads();
    unsigned short* C = (unsigned short*)Cv + (size_t)z * 4194304;
    int row = t >> 1, part = t & 1;
    unsigned short* gp = C + (size_t)(m0 + row) * 2048 + n0 + part * 64;
#pragma unroll
    for (int i = 0; i < 8; ++i) {
      int u = part * 8 + i;
      uint4 vv = *(const uint4*)&SMEM[row * 128 + ((u ^ (row & 15)) << 3)];
      *(uint4*)(gp + i * 8) = vv;
    }
  } else {  // EPI == 3: O = (P*V)/l, f32 out, two 32KB half-tiles
    float* C = (float*)Cv + (size_t)z * 2048 * 1024;
    float* SF = (float*)SMEM;           // 8192 floats = 128 rows x 64 cols
#pragma unroll
    for (int h = 0; h < 2; ++h) {
      if (h) __syncthreads();
      if ((w >> 1) == h) {
#pragma unroll
        for (int ns = 0; ns < 2; ++ns) {
          int c = ns * 32 + l31;        // local col within half
#pragma unroll
          for (int ms = 0; ms < 2; ++ms)
#pragma unroll
            for (int r = 0; r < 16; ++r) {
              int row = wm + ms * 32 + (r & 3) + ((r >> 2) << 3) + (half << 2);
              SF[row * 64 + (((c >> 2) ^ (row & 15)) << 2) + (c & 3)] =
                  acc[ms][ns][r];
            }
        }
      }
      __syncthreads();
      int row = t >> 1, part = t & 1;
      float lw = lvec[z * 2048 + m0 + row];
      float inv = lw > 0.f ? 1.f / lw : 0.f;
      float* gp = C + (size_t)(m0 + row) * 1024 + n0 + h * 64 + part * 32;
#pragma unroll
      for (int i = 0; i < 8; ++i) {
        int u = part * 8 + i;
        float4 vv = *(const float4*)&SF[row * 64 + ((u ^ (row & 15)) << 2)];
        vv.x *= inv; vv.y *= inv; vv.z *= inv; vv.w *= inv;
        *(float4*)(gp + i * 4) = vv;
      }
    }
  }
}

extern "C" void kernel_launch(void* const* d_in, const int* in_sizes, int n_in,
                              void* d_out, int out_size, void* d_ws, size_t ws_size,
                              hipStream_t stream) {
  const float* X    = (const float*)d_in[0];
  const int*   mask = (const int*)d_in[1];
  const float* Wq   = (const float*)d_in[2];
  const float* bq   = (const float*)d_in[3];
  const float* Wk   = (const float*)d_in[4];
  const float* bk   = (const float*)d_in[5];
  const float* Wv   = (const float*)d_in[6];
  const float* bv   = (const float*)d_in[7];
  float* out = (float*)d_out;

  constexpr size_t SZ = (size_t)16384 * 1024;
  unsigned short* Q    = (unsigned short*)d_ws;      // Q|K|Vt contiguous (sel<<24)
  float*          lvec = (float*)(Q + 3 * SZ);
  unsigned short* P    = (unsigned short*)(lvec + 16384);
  unsigned short* Xb   = P;               // overlaid: dead before P written
  unsigned short* Wt   = Xb + SZ;         // 3 x [1024][1024] bf16
  unsigned short* Vt   = Q + 2 * SZ;

  // 1. prep: X->bf16, W->Wt (bf16, transposed), lvec=0
  k_prep<<<dim3(17153), 256, 0, stream>>>(X, Xb, Wq, Wk, Wv, Wt, lvec);

  // 2. fused QKV projection (24 n-strips: 8 Q, 8 K, 8 V)
  k_gemm<4><<<dim3(128, 24, 1), 256, 0, stream>>>(
      Xb, Wt, (void*)Q, bq, bk, bv, nullptr, nullptr, nullptr,
      0, 0, 1024, 1024, 16);

  // 3. P = exp(Q K^T) masked + atomic row sums
  k_gemm<2><<<dim3(16, 16, 8), 256, 0, stream>>>(
      Q, Q + SZ, (void*)P, nullptr, nullptr, nullptr, nullptr, lvec, mask,
      2048 * 1024, 2048 * 1024, 1024, 1024, 16);

  // 4. O = (P V) / l  -> fp32 out
  k_gemm<3><<<dim3(16, 8, 8), 256, 0, stream>>>(
      P, Vt, (void*)out, nullptr, nullptr, nullptr, lvec, nullptr, nullptr,
      2048 * 2048, 1024 * 2048, 2048, 2048, 32);
}